// Round 14
// baseline (201.433 us; speedup 1.0000x reference)
//
#include <hip/hip_runtime.h>

typedef unsigned short u16;
typedef unsigned int   u32;
typedef u16  u16x8 __attribute__((ext_vector_type(8)));
typedef u16  u16x4 __attribute__((ext_vector_type(4)));
typedef float f32x4 __attribute__((ext_vector_type(4)));
typedef __bf16 bf16x8 __attribute__((ext_vector_type(8)));

#define SEQ   512
#define DIM   512
#define DHEAD 64
#define M_ROWS 16384   // 4*8*512

#define AS1 __attribute__((address_space(1)))
#define AS3 __attribute__((address_space(3)))
// async global->LDS, 16B per lane, LDS dest = wave-uniform base + lane*16
#define GLL16(gp, lp) __builtin_amdgcn_global_load_lds((const AS1 void*)(gp), (AS3 void*)(lp), 16, 0, 0)

// counted-vmcnt barrier pair for the 2-phase pipeline (prefetch stays in
// flight across the barrier; NEVER vmcnt(0) in-loop)
#define WAIT_VM_BAR(LIT) do { asm volatile("s_waitcnt vmcnt(" LIT ")" ::: "memory"); __builtin_amdgcn_s_barrier(); } while (0)
#define LGKM_BAR()       do { asm volatile("s_waitcnt lgkmcnt(0)" ::: "memory"); __builtin_amdgcn_s_barrier(); } while (0)

__device__ __forceinline__ u16 f2b(float f) {
  u32 x = __builtin_bit_cast(u32, f);
  return (u16)((x + 0x7fffu + ((x >> 16) & 1u)) >> 16);
}

// ---------------------------------------------------------------------------
// Kernel 0: prep = weight transpose ONLY, fp32 [K,N] -> bf16 [N,K].
// Input fp32->bf16 conversion is fused into gemm_qkv's staging (reg-cvt
// path) — deletes the ~200MB input streaming pass. R12's lesson is kept:
// the 2-phase LDS staging machine stays; only the transport into LDS for
// the fp32 operand changes (global->reg->cvt->ds_write, T14-style).
// ---------------------------------------------------------------------------
__global__ __launch_bounds__(256) void prep(const float* __restrict__ Wq,
                                            const float* __restrict__ Wk,
                                            const float* __restrict__ Wv,
                                            const float* __restrict__ Wo,
                                            u16* __restrict__ wout) {
  __shared__ float tile[32][33];
  const int bid = blockIdx.x;          // 0..1023
  const int z = bid >> 8;              // weight index 0..3
  const int t = bid & 255;
  const int n0 = (t & 15) * 32;
  const int k0 = (t >> 4) * 32;
  const int tid = threadIdx.x;
  const int tx = tid & 31, ty = tid >> 5;
  const float* W = (z == 0) ? Wq : (z == 1) ? Wk : (z == 2) ? Wv : Wo;
#pragma unroll
  for (int i = 0; i < 4; i++) {
    int r = ty + i * 8;
    tile[r][tx] = W[(k0 + r) * DIM + n0 + tx];
  }
  __syncthreads();
  u16* o = wout + (size_t)z * DIM * DIM;
#pragma unroll
  for (int i = 0; i < 4; i++) {
    int r = ty + i * 8;
    o[(n0 + r) * DIM + k0 + tx] = f2b(tile[tx][r]);
  }
}

// ---------------------------------------------------------------------------
// Kernel 1: fused Q/K/V^T projection GEMM with FUSED INPUT CONVERSION.
// Same proven 128x128 2-phase template as R13 (LDS 32KB, 5 blocks/CU,
// vmcnt-counted barriers, XCD swizzle). The fp32 operand (inputs) is
// staged global->reg (4x float4, issued with the k+1 prefetch, latency
// hidden under tile-k compute) -> f2b (bit-identical to old prep) ->
// ds_write_b128 into the SAME bf16 [128x32] layout. The bf16 operand
// (weights) keeps GLL16. Fragment reads and MFMA loop untouched.
// Per-iter vmem: 4 F-loads + 2 H-GLL16 = 6; top-of-iter vmcnt(6) drains
// only the previous tile's GLL16 pair.
//  z=0: Qb = Qin_f32 @ Wq   z=1: Kb = KVin_f32 @ Wk
//  z=2: Vt[512,M] = Wvt . KVin_f32^T
// ---------------------------------------------------------------------------
__global__ __launch_bounds__(256, 2) void gemm_qkv(const float* __restrict__ Qin,
                                                   const float* __restrict__ KVin,
                                                   const u16* __restrict__ Wqt,
                                                   const u16* __restrict__ Wkt,
                                                   const u16* __restrict__ Wvt,
                                                   u16* __restrict__ Qb,
                                                   u16* __restrict__ Kb,
                                                   u16* __restrict__ Vt) {
  __shared__ __attribute__((aligned(16))) u16 Fs[2][128 * 32];   // fp32-operand tile (bf16)
  __shared__ __attribute__((aligned(16))) u16 Hs[2][128 * 32];   // bf16-operand tile
  const int tid = threadIdx.x;
  const int lane = tid & 63;
  const int w = tid >> 6;
  const int l15 = lane & 15;
  const int quad = lane >> 4;
  const int z = blockIdx.z;
  const int d = blockIdx.x;                  // 0..511
  const int bid = (d & 7) * 64 + (d >> 3);   // XCD swizzle, bijective on 512
  const int wr = (w >> 1) * 64, wc = (w & 1) * 64;
  const int srow = lane >> 2;
  const int scol = (lane & 3) * 8;

  int gm, gn;
  if (z < 2) { gm = (bid >> 2) * 128;  gn = (bid & 3) * 128; }   // 128 m x 4 n
  else       { gm = (bid & 3) * 128;   gn = (bid >> 2) * 128; }  // 4 m x 128 n
  const float* F = (z == 0) ? Qin : KVin;                        // fp32 operand
  const u16*   H = (z == 0) ? Wqt : (z == 1) ? Wkt : Wvt;        // bf16 operand
  const int fbase = (z < 2) ? gm : gn;   // fp32 operand row base
  const int hbase = (z < 2) ? gn : gm;   // bf16 operand row base
  const int frow = fbase + w * 32 + (lane >> 2);   // lane's fp32 row (chunk 0)
  const int fcol = (lane & 3) * 8;                 // lane's 8-float column

  f32x4 acc[4][4] = {};
  float4 fa[2], fb[2];   // in-flight fp32 fragments (16 VGPR)

  // issue fp32 loads for step kk (held in regs until WRITE_F)
  auto LOAD_F = [&](int kk) {
#pragma unroll
    for (int i = 0; i < 2; i++) {
      const float* fp = &F[(size_t)(frow + i * 16) * DIM + kk * 32 + fcol];
      fa[i] = *reinterpret_cast<const float4*>(fp);
      fb[i] = *reinterpret_cast<const float4*>(fp + 4);
    }
  };
  auto STAGE_H = [&](int kk, int b) {
#pragma unroll
    for (int i = 0; i < 2; i++) {
      int r0 = w * 32 + i * 16;
      GLL16(&H[(size_t)(hbase + r0 + srow) * DIM + kk * 32 + scol], &Hs[b][r0 * 32]);
    }
  };
  auto WRITE_F = [&](int b) {
#pragma unroll
    for (int i = 0; i < 2; i++) {
      u16x8 v;
      v[0] = f2b(fa[i].x); v[1] = f2b(fa[i].y); v[2] = f2b(fa[i].z); v[3] = f2b(fa[i].w);
      v[4] = f2b(fb[i].x); v[5] = f2b(fb[i].y); v[6] = f2b(fb[i].z); v[7] = f2b(fb[i].w);
      *reinterpret_cast<u16x8*>(&Fs[b][(w * 32 + i * 16 + (lane >> 2)) * 32 + fcol]) = v;
    }
  };

  // prologue: tile 0 staged; lgkm fence so iter-0's barrier publishes Fs[0]
  LOAD_F(0);
  STAGE_H(0, 0);
  WRITE_F(0);                        // compiler inserts the vmcnt wait for fa/fb
  asm volatile("s_waitcnt lgkmcnt(0)" ::: "memory");

  for (int kk = 0; kk < 16; kk++) {
    const int cur = kk & 1;
    if (kk < 15) {
      LOAD_F(kk + 1);                // F(k+1) -> regs, hidden under compute
      STAGE_H(kk + 1, cur ^ 1);      // H(k+1) -> LDS via GLL16
      WAIT_VM_BAR("6");              // drains H(kk); our 6 new ops stay in flight
    } else {
      WAIT_VM_BAR("0");
    }

    const u16* Am = (z < 2) ? Fs[cur] : Hs[cur];
    const u16* Bn = (z < 2) ? Hs[cur] : Fs[cur];
    bf16x8 af[4], bfr[4];
#pragma unroll
    for (int mt = 0; mt < 4; mt++)
      af[mt] = *reinterpret_cast<const bf16x8*>(&Am[(wr + mt * 16 + l15) * 32 + quad * 8]);
#pragma unroll
    for (int nt = 0; nt < 4; nt++)
      bfr[nt] = *reinterpret_cast<const bf16x8*>(&Bn[(wc + nt * 16 + l15) * 32 + quad * 8]);
#pragma unroll
    for (int mt = 0; mt < 4; mt++)
#pragma unroll
      for (int nt = 0; nt < 4; nt++)
        acc[mt][nt] = __builtin_amdgcn_mfma_f32_16x16x32_bf16(af[mt], bfr[nt], acc[mt][nt], 0, 0, 0);

    if (kk < 15) WRITE_F(cur ^ 1);   // cvt+write F(k+1); loads landed during compute
    LGKM_BAR();                      // ds reads/writes drained; no vm drain
  }

  if (z < 2) {
    u16* C = (z == 0) ? Qb : Kb;
#pragma unroll
    for (int mt = 0; mt < 4; mt++)
#pragma unroll
      for (int nt = 0; nt < 4; nt++)
#pragma unroll
        for (int r = 0; r < 4; r++)
          C[(size_t)(gm + wr + mt * 16 + quad * 4 + r) * DIM + gn + wc + nt * 16 + l15] = f2b(acc[mt][nt][r]);
  } else {
#pragma unroll
    for (int mt = 0; mt < 4; mt++)
#pragma unroll
      for (int nt = 0; nt < 4; nt++)
#pragma unroll
        for (int r = 0; r < 4; r++)
          Vt[(size_t)(gm + wr + mt * 16 + quad * 4 + r) * M_ROWS + gn + wc + nt * 16 + l15] = f2b(acc[mt][nt][r]);
  }
}

// ---------------------------------------------------------------------------
// Kernel 2: flash attention — R9/R13 VERBATIM (GLL16 single-buffer KVBLK=64,
// per-g Pq planes, no fences, XCD swizzle, static-base exp2 softmax).
// ---------------------------------------------------------------------------
__global__ __launch_bounds__(256) void attn(const u16* __restrict__ Qb,
                                            const u16* __restrict__ Kb,
                                            const u16* __restrict__ Vtg,
                                            u16* __restrict__ Ob) {
  __shared__ __attribute__((aligned(16))) u16 Ks[2 * 64 * 32];    // [kd-plane][key][32]
  __shared__ __attribute__((aligned(16))) u16 Vs[2 * 64 * 32];    // [key-plane][d][32]
  __shared__ __attribute__((aligned(16))) u16 Pq[4][2][16 * 72];  // per-wave, per-g

  const int tid = threadIdx.x;
  const int lane = tid & 63;
  const int w = tid >> 6;
  const int l15 = lane & 15;
  const int quad = lane >> 4;
  const int srow = lane >> 2;
  const int scol = (lane & 3) * 8;

  // XCD swizzle: hw index d -> logical bid = (d&7)*128 + (d>>3). Bijective on
  // [0,1024). Panel group {4p..4p+3} maps to hw indices differing by 8 ->
  // same XCD under round-robin dispatch. Perf-only (any mapping is correct).
  const int d = blockIdx.x;
  const int bid = (d & 7) * 128 + (d >> 3);
  const int qt = bid & 3;            // 4 q-tiles of 128 rows
  const int bhp = bid >> 2;
  const int h = bhp & 7;
  const int bp = bhp >> 3;           // 0..31
  const int qrow0 = bp * SEQ + qt * 128;
  const int col0 = h * DHEAD;

  const float SCL = 0.18033688011112042f;   // 0.125 * log2(e)

  // Q fragments direct from global (B-operand layout: lane holds q=l15)
  bf16x8 qf[2][2];
#pragma unroll
  for (int g = 0; g < 2; g++)
#pragma unroll
    for (int kd = 0; kd < 2; kd++)
      qf[g][kd] = *reinterpret_cast<const bf16x8*>(
          &Qb[(size_t)(qrow0 + w * 32 + g * 16 + l15) * DIM + col0 + kd * 32 + quad * 8]);

  float l_[2] = {0.0f, 0.0f};
  f32x4 o[2][4] = {};

  for (int j = 0; j < 8; j++) {
    __syncthreads();
    const int krow0 = bp * SEQ + j * 64;
    // K staging: 8 GLL16 (plane=kd 0..1, 16-key chunk 0..3); wave w: t=2w..2w+1
#pragma unroll
    for (int i = 0; i < 2; i++) {
      int t = w * 2 + i;
      int plane = t & 1, chunk = t >> 1;
      GLL16(&Kb[(size_t)(krow0 + chunk * 16 + srow) * DIM + col0 + plane * 32 + scol],
            &Ks[plane * 2048 + chunk * 512]);
    }
    // V staging: 8 GLL16 (plane=32-key chunk 0..1, chunk=16-d chunk 0..3)
#pragma unroll
    for (int i = 0; i < 2; i++) {
      int t = w * 2 + i;
      int plane = t & 1, chunk = t >> 1;
      GLL16(&Vtg[(size_t)(col0 + chunk * 16 + srow) * M_ROWS + krow0 + plane * 32 + scol],
            &Vs[plane * 2048 + chunk * 512]);
    }
    __syncthreads();

#pragma unroll
    for (int g = 0; g < 2; g++) {
      // S^T = K*Q^T : 4 key-tiles of 16; D[key][q=l15]; scale has log2e folded
      f32x4 st[4];
#pragma unroll
      for (int ct = 0; ct < 4; ct++) {
        f32x4 z = {};
#pragma unroll
        for (int kd = 0; kd < 2; kd++) {
          bf16x8 kf = *reinterpret_cast<const bf16x8*>(&Ks[kd * 2048 + (ct * 16 + l15) * 32 + quad * 8]);
          z = __builtin_amdgcn_mfma_f32_16x16x32_bf16(kf, qf[g][kd], z, 0, 0, 0);
        }
        st[ct] = z * SCL;
      }

      // static-base softmax: P = 2^st directly (no max track, no rescale);
      // row-sum reduced across quads (q=l15 holds 16 keys/lane)
      float rs = 0.0f;
#pragma unroll
      for (int ct = 0; ct < 4; ct++)
#pragma unroll
        for (int r = 0; r < 4; r++) {
          float pv = __builtin_amdgcn_exp2f(st[ct][r]);
          st[ct][r] = pv;
          rs += pv;
        }
      rs += __shfl_xor(rs, 16);
      rs += __shfl_xor(rs, 32);
      l_[g] += rs;

      // P^T (C-layout) -> Pq[w][g][q][key], packed b64 stores. No fence:
      // per-g buffer => no reuse hazard; same-wave store->read ordering is
      // a visible data dependence the compiler handles with lgkmcnt(N).
#pragma unroll
      for (int ct = 0; ct < 4; ct++) {
        u16x4 pk;
#pragma unroll
        for (int e = 0; e < 4; e++) pk[e] = f2b(st[ct][e]);
        *reinterpret_cast<u16x4*>(&Pq[w][g][l15 * 72 + ct * 16 + quad * 4]) = pk;
      }

      // O += P*V : A = Pq[w][g][q=l15][key], B = Vs plane c2 [d][key-chunk]
#pragma unroll
      for (int c2 = 0; c2 < 2; c2++) {
        bf16x8 af = *reinterpret_cast<const bf16x8*>(&Pq[w][g][l15 * 72 + c2 * 32 + quad * 8]);
#pragma unroll
        for (int nt = 0; nt < 4; nt++) {
          bf16x8 bv = *reinterpret_cast<const bf16x8*>(&Vs[c2 * 2048 + (nt * 16 + l15) * 32 + quad * 8]);
          o[g][nt] = __builtin_amdgcn_mfma_f32_16x16x32_bf16(af, bv, o[g][nt], 0, 0, 0);
        }
      }
    }
  }

  // epilogue: normalize and write bf16 [M,512]
#pragma unroll
  for (int g = 0; g < 2; g++) {
    float inv = 1.0f / l_[g];
#pragma unroll
    for (int r = 0; r < 4; r++) {
      float lr = __shfl(inv, quad * 4 + r);
      int row = qrow0 + w * 32 + g * 16 + quad * 4 + r;
#pragma unroll
      for (int nt = 0; nt < 4; nt++)
        Ob[(size_t)row * DIM + col0 + nt * 16 + l15] = f2b(o[g][nt][r] * lr);
    }
  }
}

// ---------------------------------------------------------------------------
// Kernel 3: output GEMM, 2-phase double-buffered staging + XCD swizzle
// (1-D grid 512; blocks sharing an Ob A-panel were consecutive in x).
// fp32 epilogue + bias.
// ---------------------------------------------------------------------------
__global__ __launch_bounds__(256) void gemm_out(const u16* __restrict__ Ab,
                                                const u16* __restrict__ Bt,
                                                const float* __restrict__ bias,
                                                float* __restrict__ C) {
  __shared__ __attribute__((aligned(16))) u16 As[2][128 * 32];
  __shared__ __attribute__((aligned(16))) u16 Bs[2][128 * 32];
  const int tid = threadIdx.x;
  const int lane = tid & 63;
  const int w = tid >> 6;
  const int l15 = lane & 15;
  const int quad = lane >> 4;
  const int d = blockIdx.x;                  // 0..511
  const int bid = (d & 7) * 64 + (d >> 3);   // XCD swizzle, bijective on 512
  const int gn = (bid & 3) * 128;
  const int gm = (bid >> 2) * 128;
  const int wr = (w >> 1) * 64, wc = (w & 1) * 64;
  const int srow = lane >> 2;
  const int scol = (lane & 3) * 8;

  f32x4 acc[4][4] = {};

  // stage K-step kk into buffer b: 4 GLL16 per wave (2 A + 2 B)
  auto stage = [&](int kk, int b) {
    const int k0 = kk * 32;
#pragma unroll
    for (int i = 0; i < 2; i++) {
      int r0 = w * 32 + i * 16;
      GLL16(&Ab[(size_t)(gm + r0 + srow) * DIM + k0 + scol], &As[b][r0 * 32]);
      GLL16(&Bt[(size_t)(gn + r0 + srow) * DIM + k0 + scol], &Bs[b][r0 * 32]);
    }
  };

  stage(0, 0);
  for (int kk = 0; kk < 16; kk++) {
    const int cur = kk & 1;
    if (kk < 15) {
      stage(kk + 1, cur ^ 1);
      WAIT_VM_BAR("4");
    } else {
      WAIT_VM_BAR("0");
    }

    bf16x8 af[4], bfr[4];
#pragma unroll
    for (int mt = 0; mt < 4; mt++)
      af[mt] = *reinterpret_cast<const bf16x8*>(&As[cur][(wr + mt * 16 + l15) * 32 + quad * 8]);
#pragma unroll
    for (int nt = 0; nt < 4; nt++)
      bfr[nt] = *reinterpret_cast<const bf16x8*>(&Bs[cur][(wc + nt * 16 + l15) * 32 + quad * 8]);
#pragma unroll
    for (int mt = 0; mt < 4; mt++)
#pragma unroll
      for (int nt = 0; nt < 4; nt++)
        acc[mt][nt] = __builtin_amdgcn_mfma_f32_16x16x32_bf16(af[mt], bfr[nt], acc[mt][nt], 0, 0, 0);

    LGKM_BAR();
  }

#pragma unroll
  for (int mt = 0; mt < 4; mt++)
#pragma unroll
    for (int nt = 0; nt < 4; nt++) {
      float bcol = bias[gn + wc + nt * 16 + l15];
#pragma unroll
      for (int r = 0; r < 4; r++)
        C[(size_t)(gm + wr + mt * 16 + quad * 4 + r) * DIM + gn + wc + nt * 16 + l15] = acc[mt][nt][r] + bcol;
    }
}

// ---------------------------------------------------------------------------
extern "C" void kernel_launch(void* const* d_in, const int* in_sizes, int n_in,
                              void* d_out, int out_size, void* d_ws, size_t ws_size,
                              hipStream_t stream) {
  const float* q_in  = (const float*)d_in[0];
  const float* kv_in = (const float*)d_in[1];
  const float* Wq    = (const float*)d_in[2];
  const float* Wk    = (const float*)d_in[3];
  const float* Wv    = (const float*)d_in[4];
  const float* Wo    = (const float*)d_in[5];
  const float* bo    = (const float*)d_in[6];
  float* out = (float*)d_out;

  u16* ws = (u16*)d_ws;
  u16* Wqt = ws;
  u16* Wkt = ws + 262144;
  u16* Wvt = ws + 524288;
  u16* Wot = ws + 786432;
  u16* Qb  = ws + 1048576;
  u16* Kb  = Qb + (size_t)M_ROWS * DIM;
  u16* Vtg = Kb + (size_t)M_ROWS * DIM;
  u16* Ob  = Vtg + (size_t)M_ROWS * DIM;

  prep<<<dim3(1024), 256, 0, stream>>>(Wq, Wk, Wv, Wo, ws);
  gemm_qkv<<<dim3(512, 1, 3), 256, 0, stream>>>(q_in, kv_in, Wqt, Wkt, Wvt, Qb, Kb, Vtg);
  attn<<<dim3(1024), 256, 0, stream>>>(Qb, Kb, Vtg, Ob);
  gemm_out<<<dim3(512), 256, 0, stream>>>(Ob, Wot, bo, out);
}